// Round 6
// baseline (123.177 us; speedup 1.0000x reference)
//
#include <hip/hip_runtime.h>
#include <math.h>

#define B_ 8
#define L_ 200
#define H_ 128
#define NH_ 2
#define HD_ 64
#define LP_ 256   // padded L (pad region never zeroed; OOB contributions discarded)
#define TV_ 32    // time vocab
#define RQ_ 8     // rows per qkv block

// ---------------------------------------------------------------- fused QKV
// grid (B*L/RQ_, 3), 128 threads; m = 0:Q, 1:K(transposed), 2:V
__global__ __launch_bounds__(128)
void qkv_kernel(const float* __restrict__ X,
                const float* __restrict__ Wq, const float* __restrict__ bq,
                const float* __restrict__ Wk, const float* __restrict__ bk,
                const float* __restrict__ Wv, const float* __restrict__ bv,
                const float* __restrict__ kpt, const float* __restrict__ vpt,
                float* __restrict__ Q, float* __restrict__ Kt, float* __restrict__ Vp){
    const int r0 = blockIdx.x * RQ_;
    const int m  = blockIdx.y;
    const int j  = threadIdx.x;
    __shared__ float xs[RQ_][H_];
    #pragma unroll
    for (int r = 0; r < RQ_; ++r) xs[r][j] = X[(r0 + r) * H_ + j];
    __syncthreads();
    const float* W = (m == 0) ? Wq : ((m == 1) ? Wk : Wv);
    float acc[RQ_];
    #pragma unroll
    for (int r = 0; r < RQ_; ++r) acc[r] = 0.f;
    #pragma unroll 8
    for (int i = 0; i < H_; ++i) {
        const float w = W[i * H_ + j];
        #pragma unroll
        for (int r = 0; r < RQ_; ++r) acc[r] += xs[r][i] * w;
    }
    const int h = j >> 6, d = j & 63;
    if (m == 0) {
        const float bj = bq[j];
        #pragma unroll
        for (int r = 0; r < RQ_; ++r) Q[(r0 + r) * H_ + j] = acc[r] + bj;
    } else if (m == 1) {
        const float bj = bk[j];
        #pragma unroll
        for (int r = 0; r < RQ_; ++r) {
            const int row = r0 + r, b = row / L_, l = row % L_;
            Kt[((b * NH_ + h) * HD_ + d) * LP_ + l] = acc[r] + bj + kpt[l * H_ + j];
        }
    } else {
        const float bj = bv[j];
        #pragma unroll
        for (int r = 0; r < RQ_; ++r) {
            const int row = r0 + r, b = row / L_, l = row % L_;
            Vp[((b * NH_ + h) * L_ + l) * HD_ + d] = acc[r] + bj + vpt[l * H_ + j];
        }
    }
}

// ------------------------------------------- fused attention + out-proj + LN
// grid = B*(L/4) = 400 blocks of 512 threads (8 waves), one (head,q) per wave.
// Table staging issues first, but phase A (Kt dot) runs BEFORE the barrier so
// the staging latency is hidden under phase-A compute.
__global__ __launch_bounds__(512)
void attn_out_kernel(const float* __restrict__ Q, const float* __restrict__ Kt,
                     const float* __restrict__ Vp, const int* __restrict__ tseq,
                     const float* __restrict__ mask,
                     const float* __restrict__ ktt, const float* __restrict__ vtt,
                     const float* __restrict__ Wd, const float* __restrict__ bd,
                     const float* __restrict__ X, const float* __restrict__ g,
                     const float* __restrict__ bb, float* __restrict__ out){
    const int b  = blockIdx.x / (L_ / 4);
    const int q0 = (blockIdx.x % (L_ / 4)) * 4;
    const int w  = threadIdx.x >> 6, lane = threadIdx.x & 63;
    const int h  = w & 1, qr = w >> 1;      // 8 waves: (h, qr) = (w&1, w>>1)
    const int q  = q0 + qr;
    const int bh = b * NH_ + h;

    __shared__ float ktt_s[TV_][H_ + 1];    // +1 pad: qkt access conflict-free
    __shared__ float vtt_s[TV_][H_ + 1];
    __shared__ __align__(16) float qs [8][HD_];
    __shared__ float qkt[8][TV_];
    __shared__ float ss [8][TV_];
    __shared__ __align__(16) float ps [8][LP_];
    __shared__ __align__(16) float ctx_s[4][H_];
    __shared__ float red1[8], red2[8];

    // 1) issue table staging (coalesced; completes under phase A)
    #pragma unroll
    for (int t = threadIdx.x; t < TV_ * H_; t += 512) {
        ktt_s[t >> 7][t & 127] = ktt[t];
        vtt_s[t >> 7][t & 127] = vtt[t];
    }
    // 2) per-wave q vector (same-wave LDS, no barrier needed)
    qs[w][lane] = Q[(b * L_ + q) * H_ + h * HD_ + lane];
    if (lane < TV_) ss[w][lane] = 0.f;

    // 3) phase A BEFORE barrier: lane handles k = 4*lane .. 4*lane+3
    const float4* kt4 = (const float4*)(Kt + (size_t)bh * HD_ * LP_);
    float4 sA = make_float4(0.f, 0.f, 0.f, 0.f);
    float4 sB = make_float4(0.f, 0.f, 0.f, 0.f);
    #pragma unroll 8
    for (int d = 0; d < HD_; d += 2) {
        const float q0d = qs[w][d], q1d = qs[w][d + 1];
        const float4 k0 = kt4[d * (LP_ / 4) + lane];
        const float4 k1 = kt4[(d + 1) * (LP_ / 4) + lane];
        sA.x += q0d * k0.x; sA.y += q0d * k0.y; sA.z += q0d * k0.z; sA.w += q0d * k0.w;
        sB.x += q1d * k1.x; sB.y += q1d * k1.y; sB.z += q1d * k1.z; sB.w += q1d * k1.w;
    }
    float sv[4] = {sA.x + sB.x, sA.y + sB.y, sA.z + sB.z, sA.w + sB.w};
    const int k0i = lane * 4;

    // 4) prefetch mask/tseq rows (independent of tables)
    float mv[4]; int tk[4]; int tq = 0;
    if (k0i < L_) {   // lanes 0..49; rows 800B-aligned -> float4/int4 ok
        const float4 m4 = ((const float4*)(mask + ((size_t)(b * L_ + q)) * L_))[lane];
        const int4   t4 = ((const int4*)(tseq + b * L_))[lane];
        tq = tseq[b * L_ + q];
        mv[0] = m4.x; mv[1] = m4.y; mv[2] = m4.z; mv[3] = m4.w;
        tk[0] = t4.x; tk[1] = t4.y; tk[2] = t4.z; tk[3] = t4.w;
    }
    __syncthreads();   // tables ready (latency hidden by phase A)

    // 5) qkt[i] = dot(q, ktt[i, head slice]); bucket = lane&31, half = lane>>5
    {
        const int i = lane & 31, half = lane >> 5;
        float a = 0.f;
        #pragma unroll 8
        for (int d = 0; d < 32; ++d)
            a += qs[w][half * 32 + d] * ktt_s[i][h * HD_ + half * 32 + d];
        a += __shfl_xor(a, 32);
        if (lane < TV_) qkt[w][lane] = a;
    }

    // 6) combine scores, bucket sums, softmax
    float mx = -INFINITY;
    if (k0i < L_) {
        #pragma unroll
        for (int jj = 0; jj < 4; ++jj) {
            int dt = tq - tk[jj]; if (dt < 0) dt = -dt;
            int idx = (int)log1pf((float)dt);
            if (idx > TV_ - 1) idx = TV_ - 1;
            float s = (sv[jj] + qkt[w][idx]) * 0.125f + mv[jj];
            sv[jj] = s;
            atomicAdd(&ss[w][idx], s);          // pre-softmax bucket sums
            if (s > mx) mx = s;
        }
    } else {
        sv[0] = sv[1] = sv[2] = sv[3] = -INFINITY;
    }
    for (int off = 32; off; off >>= 1) { float o = __shfl_xor(mx, off); if (o > mx) mx = o; }
    float sum = 0.f, ev[4];
    #pragma unroll
    for (int jj = 0; jj < 4; ++jj) {
        float e = (k0i + jj < L_) ? __expf(sv[jj] - mx) : 0.f;
        ev[jj] = e; sum += e;
    }
    for (int off = 32; off; off >>= 1) sum += __shfl_xor(sum, off);
    ((float4*)ps[w])[lane] = make_float4(ev[0], ev[1], ev[2], ev[3]);

    // 7) phase B: lane = d (ps/ss same-wave LDS, ordered)
    const float inv = 1.f / sum;
    const float* vp = Vp + (size_t)bh * L_ * HD_;
    const float4* ps4 = (const float4*)ps[w];
    float c = 0.f;
    #pragma unroll 5
    for (int k4 = 0; k4 < L_ / 4; ++k4) {
        const float4 p = ps4[k4];
        const int kb = k4 * 4;
        c += p.x * vp[(kb + 0) * HD_ + lane];
        c += p.y * vp[(kb + 1) * HD_ + lane];
        c += p.z * vp[(kb + 2) * HD_ + lane];
        c += p.w * vp[(kb + 3) * HD_ + lane];
    }
    c *= inv;
    float tc = 0.f;
    const float4* ss4 = (const float4*)ss[w];
    #pragma unroll
    for (int i4 = 0; i4 < TV_ / 4; ++i4) {
        const float4 z = ss4[i4];
        const int i = i4 * 4;
        tc += z.x * vtt_s[i + 0][h * HD_ + lane];
        tc += z.y * vtt_s[i + 1][h * HD_ + lane];
        tc += z.z * vtt_s[i + 2][h * HD_ + lane];
        tc += z.w * vtt_s[i + 3][h * HD_ + lane];
    }
    ctx_s[qr][h * HD_ + lane] = c + tc;
    __syncthreads();

    // 8) out projection + residual + LayerNorm (4 rows x 128 cols)
    const int r = threadIdx.x >> 7, j = threadIdx.x & 127;
    const float4* c4 = (const float4*)ctx_s[r];
    float acc = 0.f;
    #pragma unroll 8
    for (int i4 = 0; i4 < H_ / 4; ++i4) {
        const float4 xv = c4[i4];
        const int i = i4 * 4;
        acc += xv.x * Wd[(i + 0) * H_ + j];
        acc += xv.y * Wd[(i + 1) * H_ + j];
        acc += xv.z * Wd[(i + 2) * H_ + j];
        acc += xv.w * Wd[(i + 3) * H_ + j];
    }
    const int row = b * L_ + q0 + r;
    const float x = acc + bd[j] + X[row * H_ + j];

    float s = x;
    for (int off = 32; off; off >>= 1) s += __shfl_xor(s, off);
    if (lane == 0) red1[w] = s;
    __syncthreads();
    const float mean = (red1[2 * r] + red1[2 * r + 1]) * (1.f / H_);
    const float dx = x - mean;
    float s2 = dx * dx;
    for (int off = 32; off; off >>= 1) s2 += __shfl_xor(s2, off);
    if (lane == 0) red2[w] = s2;
    __syncthreads();
    const float var = (red2[2 * r] + red2[2 * r + 1]) * (1.f / H_);
    const float y = dx * rsqrtf(var + 1e-12f) * g[j] + bb[j];
    out[row * H_ + j] = y;
}

// ---------------------------------------------------------------- launch
extern "C" void kernel_launch(void* const* d_in, const int* in_sizes, int n_in,
                              void* d_out, int out_size, void* d_ws, size_t ws_size,
                              hipStream_t stream) {
    const float* X    = (const float*)d_in[0];
    const int*   tseq = (const int*)  d_in[1];
    const float* mask = (const float*)d_in[2];
    const float* Wq = (const float*)d_in[3],  *bq = (const float*)d_in[4];
    const float* Wk = (const float*)d_in[5],  *bk = (const float*)d_in[6];
    const float* Wv = (const float*)d_in[7],  *bv = (const float*)d_in[8];
    const float* Wd = (const float*)d_in[9],  *bd = (const float*)d_in[10];
    const float* g  = (const float*)d_in[11], *bb = (const float*)d_in[12];
    const float* ktt = (const float*)d_in[13], *vtt = (const float*)d_in[14];
    const float* kpt = (const float*)d_in[15], *vpt = (const float*)d_in[16];

    float* ws  = (float*)d_ws;
    float* Q   = ws;                          // B*L*H      = 204800
    float* Kt  = Q   + B_ * L_ * H_;          // B*NH*HD*LP = 262144 (pad unzeroed, by design)
    float* Vp  = Kt  + B_ * NH_ * HD_ * LP_;  // B*L*H      = 204800

    dim3 g1(B_ * L_ / RQ_, 3);
    qkv_kernel<<<g1, 128, 0, stream>>>(X, Wq, bq, Wk, bk, Wv, bv, kpt, vpt, Q, Kt, Vp);
    attn_out_kernel<<<B_ * (L_ / 4), 512, 0, stream>>>(Q, Kt, Vp, tseq, mask, ktt, vtt,
                                                       Wd, bd, X, g, bb, (float*)d_out);
}